// Round 11
// baseline (165.134 us; speedup 1.0000x reference)
//
#include <hip/hip_runtime.h>
#include <hip/hip_bf16.h>
#include <math.h>

typedef unsigned short u16;
typedef _Float16 f16x8 __attribute__((ext_vector_type(8)));
typedef float    f32x16 __attribute__((ext_vector_type(16)));
typedef u16      u16x8  __attribute__((ext_vector_type(8)));
typedef u16      u16x4  __attribute__((ext_vector_type(4)));

#define BATCH 16
#define T0 64000
#define T1 32000
#define T2 16000
#define T3 8000
#define NT3 250          // t3 outputs per mega block; 32 x 16 = 512 blocks, 2/CU
#define NBLKX 32
#define NROWS1 1040      // local y1 rows staged (520 LDS lines)
#define NMEGA (NBLKX * BATCH)

static __device__ __forceinline__ u16 f2h(float f) {
    _Float16 h = (_Float16)f;
    u16 u;
    __builtin_memcpy(&u, &h, 2);
    return u;
}

// ---------------- weight prep (f16, transposed) + pooled/counter zero-init
// a2t[kk][g][o][j]: kk 0..8, g=0..3, o=0..63, j=0..7   18432 u16
// a3t[kk][g][o][j]: kk 0..8, g=0..7, o=0..127, j=0..7  73728 u16
__global__ __launch_bounds__(256) void prep_w_k(const float* __restrict__ w2,
                                                const float* __restrict__ w3,
                                                u16* __restrict__ a2t,
                                                u16* __restrict__ a3t,
                                                float* __restrict__ pooled,
                                                int* __restrict__ counter) {
    int idx = blockIdx.x * 256 + threadIdx.x;
    if (idx < 18432) {
        int j = idx & 7, o = (idx >> 3) & 63, g = (idx >> 9) & 3, kk = idx >> 11;
        a2t[idx] = f2h(w2[(o * 32 + g * 8 + j) * 9 + kk]);
    } else if (idx < 18432 + 73728) {
        int jdx = idx - 18432;
        int j = jdx & 7, o = (jdx >> 3) & 127, g = (jdx >> 10) & 7, kk = jdx >> 13;
        a3t[jdx] = f2h(w3[(o * 64 + g * 8 + j) * 9 + kk]);
    } else if (idx < 18432 + 73728 + 2048) {
        pooled[idx - 18432 - 73728] = 0.f;
    } else if (idx == 18432 + 73728 + 2048) {
        *counter = 0;
    }
}

// ---------------- mega: conv1 -> conv2 (merged chunks) -> conv3+pool -> (last) feats
// block = 512 thr (8 waves), t3 in [r0, r0+250), batch b. LDS: 520 lines x 128 B.
// Phase A: y1 rows pair-packed 2/line, slot (pp*4+g)^(rr&7).
// Phase B (merged): BOTH 256-row chunks' accumulators computed first (reads y1
// lines <= 515 < 520), ONE barrier, then writes lines 0..511, ONE barrier.
// Phase C: reads y2 lines 2*nl+kk <= 518; stale y1 lines 512..518 only reach
// cols nl >= 252 which are masked (nl >= 250).
// Registers: acc (64 AGPR) + ~60 VGPR -> 4 waves/SIMD; 66.5 KB LDS -> 2 blocks/CU.
__global__ __launch_bounds__(512, 2) void mega_k(const float* __restrict__ audio,
                                                 const float* __restrict__ w1,
                                                 const float* __restrict__ b1,
                                                 const u16* __restrict__ a2t,
                                                 const float* __restrict__ b2,
                                                 const u16* __restrict__ a3t,
                                                 const float* __restrict__ b3,
                                                 float* __restrict__ pooled,
                                                 int* __restrict__ counter,
                                                 const float* __restrict__ wl,
                                                 const float* __restrict__ bl,
                                                 float* __restrict__ amps,
                                                 float* __restrict__ nmag) {
    __shared__ u16 sm[520 * 64];           // 66,560 B
    __shared__ int s_last;
    const int tid = threadIdx.x;
    const int b = blockIdx.y;
    const int r0 = blockIdx.x * NT3;
    const int lane = tid & 63, wv = tid >> 6;          // wv 0..7
    const int ls = lane >> 5, ln = lane & 31;

    // ---- Phase A: conv1 into LDS (y1 local rows 0..1039; global t1 = 4*r0-12+l1)
    {
        const float* ar = audio + (size_t)b * T0;
        #pragma unroll
        for (int rep = 0; rep < 3; ++rep) {
            int l1 = rep * 512 + tid;
            if (l1 >= NROWS1) break;
            int t1 = 4 * r0 - 12 + l1;
            int rr = l1 >> 1, pp = l1 & 1;
            if (t1 < 0 || t1 >= T1) {
                u16x8 z;
                #pragma unroll
                for (int q = 0; q < 8; ++q) z[q] = 0;
                #pragma unroll
                for (int g = 0; g < 4; ++g) {
                    int slot = (pp * 4 + g) ^ (rr & 7);
                    *(u16x8*)(sm + rr * 64 + slot * 8) = z;
                }
            } else {
                int base = 2 * t1 - 4;
                float x[9];
                #pragma unroll
                for (int k = 0; k < 9; ++k) {
                    int t0v = base + k;
                    x[k] = (t0v >= 0 && t0v < T0) ? ar[t0v] : 0.f;
                }
                #pragma unroll
                for (int g = 0; g < 4; ++g) {
                    u16x8 v;
                    #pragma unroll
                    for (int j = 0; j < 8; ++j) {
                        int ch = g * 8 + j;
                        float acc = b1[ch];
                        #pragma unroll
                        for (int k = 0; k < 9; ++k) acc = fmaf(x[k], w1[ch * 9 + k], acc);
                        v[j] = f2h(fmaxf(acc, 0.f));
                    }
                    int slot = (pp * 4 + g) ^ (rr & 7);
                    *(u16x8*)(sm + rr * 64 + slot * 8) = v;
                }
            }
        }
    }
    __syncthreads();

    // ---- Phase B: conv2, both 256-row chunks accumulated before write-back
    {
        f32x16 acc2[2][2];                   // [chunk][mi]
        #pragma unroll
        for (int ch = 0; ch < 2; ++ch)
            #pragma unroll
            for (int mi = 0; mi < 2; ++mi)
                #pragma unroll
                for (int q = 0; q < 16; ++q) acc2[ch][mi][q] = 0.f;
        f16x8 bfB[2][2];                     // [chunk][step]
        #pragma unroll 3
        for (int kk = 0; kk < 9; ++kk) {
            int kh = kk >> 1, pp = kk & 1;
            #pragma unroll
            for (int ch = 0; ch < 2; ++ch) {
                int line = ch * 256 + 32 * wv + ln + kh;    // <= 515 < 520
                #pragma unroll
                for (int step = 0; step < 2; ++step) {
                    int slot = (pp * 4 + 2 * step + ls) ^ (line & 7);
                    bfB[ch][step] = *(const f16x8*)(sm + line * 64 + slot * 8);
                }
            }
            const u16* ap = a2t + kk * 2048;
            #pragma unroll
            for (int step = 0; step < 2; ++step) {
                f16x8 af0 = *(const f16x8*)(ap + (2 * step + ls) * 512 + ln * 8);
                f16x8 af1 = *(const f16x8*)(ap + (2 * step + ls) * 512 + (32 + ln) * 8);
                #pragma unroll
                for (int ch = 0; ch < 2; ++ch) {
                    acc2[ch][0] = __builtin_amdgcn_mfma_f32_32x32x16_f16(af0, bfB[ch][step], acc2[ch][0], 0, 0, 0);
                    acc2[ch][1] = __builtin_amdgcn_mfma_f32_32x32x16_f16(af1, bfB[ch][step], acc2[ch][1], 0, 0, 0);
                }
            }
        }
        __syncthreads();                    // ALL y1 reads done before overwrite
        #pragma unroll
        for (int ch = 0; ch < 2; ++ch) {
            int l2 = ch * 256 + 32 * wv + ln;
            int t2 = 2 * r0 - 4 + l2;
            bool valid = (t2 >= 0) && (t2 < T2);
            #pragma unroll
            for (int mi = 0; mi < 2; ++mi)
                #pragma unroll
                for (int q = 0; q < 4; ++q) {
                    u16x4 v;
                    #pragma unroll
                    for (int d = 0; d < 4; ++d) {
                        int o = 32 * mi + 8 * q + 4 * ls + d;
                        float xv = valid ? fmaxf(acc2[ch][mi][4 * q + d] + b2[o], 0.f) : 0.f;
                        v[d] = f2h(xv);
                    }
                    int gy = 4 * mi + q;
                    int sy = gy ^ ((l2 >> 1) & 7);
                    *(u16x4*)(sm + l2 * 64 + sy * 8 + ls * 4) = v;
                }
        }
        __syncthreads();
    }

    // ---- Phase C: conv3 MFMA + mean-pool (M=128 x N=256; 2x4 waves of 64x64)
    const int mh = wv & 1, nh = wv >> 1;               // mh 0..1, nh 0..3
    f32x16 acc3[2][2];
    #pragma unroll
    for (int mi = 0; mi < 2; ++mi)
        #pragma unroll
        for (int ni = 0; ni < 2; ++ni)
            #pragma unroll
            for (int q = 0; q < 16; ++q) acc3[mi][ni][q] = 0.f;

    f16x8 bf[2][4];
    #pragma unroll 3
    for (int kk = 0; kk < 9; ++kk) {
        const u16* ap = a3t + kk * 8192;
        #pragma unroll
        for (int ni = 0; ni < 2; ++ni) {
            int nl = 64 * nh + 32 * ni + ln;
            int l2 = 2 * nl + kk;                      // <= 518 < 520
            int rrC = nl + (kk >> 1);
            #pragma unroll
            for (int step = 0; step < 4; ++step) {
                int sy = (2 * step + ls) ^ (rrC & 7);
                bf[ni][step] = *(const f16x8*)(sm + l2 * 64 + sy * 8);
            }
        }
        #pragma unroll
        for (int step = 0; step < 4; ++step) {
            f16x8 af0 = *(const f16x8*)(ap + (2 * step + ls) * 1024 + (64 * mh + ln) * 8);
            f16x8 af1 = *(const f16x8*)(ap + (2 * step + ls) * 1024 + (64 * mh + 32 + ln) * 8);
            #pragma unroll
            for (int ni = 0; ni < 2; ++ni) {
                acc3[0][ni] = __builtin_amdgcn_mfma_f32_32x32x16_f16(af0, bf[ni][step], acc3[0][ni], 0, 0, 0);
                acc3[1][ni] = __builtin_amdgcn_mfma_f32_32x32x16_f16(af1, bf[ni][step], acc3[1][ni], 0, 0, 0);
            }
        }
    }

    // epilogue: bias+relu, mask nl>=250, per-wave partials -> LDS reduce -> atomics
    float loc[32];
    #pragma unroll
    for (int mi = 0; mi < 2; ++mi)
        #pragma unroll
        for (int r = 0; r < 16; ++r) {
            int o = 64 * mh + 32 * mi + (r & 3) + 8 * (r >> 2) + 4 * ls;
            float bias = b3[o];
            float s = 0.f;
            #pragma unroll
            for (int ni = 0; ni < 2; ++ni) {
                int nl = 64 * nh + 32 * ni + ln;
                float v = fmaxf(acc3[mi][ni][r] + bias, 0.f);
                s += (nl < NT3) ? v : 0.f;
            }
            loc[mi * 16 + r] = s;
        }
    __syncthreads();
    float* smf = (float*)sm;               // [4 nh][128 o][32 ln] = 64 KB <= 66,560 B
    #pragma unroll
    for (int mi = 0; mi < 2; ++mi)
        #pragma unroll
        for (int r = 0; r < 16; ++r) {
            int o = 64 * mh + 32 * mi + (r & 3) + 8 * (r >> 2) + 4 * ls;
            smf[nh * 4096 + o * 32 + ln] = loc[mi * 16 + r];
        }
    __syncthreads();
    if (tid < 128) {
        int o = tid;
        float s = 0.f;
        #pragma unroll
        for (int j = 0; j < 32; ++j) {
            int col = (j + o) & 31;
            s += smf[o * 32 + col] + smf[4096 + o * 32 + col]
               + smf[8192 + o * 32 + col] + smf[12288 + o * 32 + col];
        }
        atomicAdd(&pooled[b * 128 + o], s);
    }

    // ---- last-finishing block computes the linear head -> amps, nmag
    if (tid == 0) {
        __threadfence();                    // release our pooled adds
        int old = atomicAdd(counter, 1);
        s_last = (old == NMEGA - 1) ? 1 : 0;
    }
    __syncthreads();
    if (s_last) {
        __threadfence();                    // acquire all pooled adds
        for (int i = tid; i < 2048; i += 512) smf[i] = pooled[i] * (1.0f / 8000.0f);
        __syncthreads();
        float ft[4];
        #pragma unroll
        for (int r = 0; r < 4; ++r) {
            int id = tid + r * 512;         // b = id>>7, o = id&127
            int bb = id >> 7, oo = id & 127;
            float acc = bl[oo];
            #pragma unroll 8
            for (int i = 0; i < 128; ++i) acc = fmaf(smf[bb * 128 + i], wl[oo * 128 + i], acc);
            ft[r] = acc;
        }
        __syncthreads();
        #pragma unroll
        for (int r = 0; r < 4; ++r) {
            int id = tid + r * 512;
            int bb = id >> 7, oo = id & 127;
            if (oo < 64) smf[2048 + bb * 64 + oo] = fmaxf(ft[r], 0.f);
            else         nmag[bb * 64 + (oo - 64)] = ft[r];
        }
        __syncthreads();
        if (tid < 16) {
            float s = 0.f;
            #pragma unroll 8
            for (int j = 0; j < 64; ++j) s += smf[2048 + tid * 64 + j];
            smf[3072 + tid] = s + 1e-6f;
        }
        __syncthreads();
        #pragma unroll
        for (int r = 0; r < 4; ++r) {
            int id = tid + r * 512;
            int bb = id >> 7, oo = id & 127;
            if (oo < 64) amps[bb * 64 + oo] = fmaxf(ft[r], 0.f) / smf[3072 + bb];
        }
    }
}

// ---------------- synthesis (head precomputed by mega's last block)
__global__ __launch_bounds__(256) void synth_k(const float* __restrict__ f0,
                                               const float* __restrict__ wn,
                                               const float* __restrict__ amps,
                                               const float* __restrict__ nmag,
                                               float* __restrict__ out) {
    int tid = threadIdx.x;
    int b = blockIdx.y;
    __shared__ float sa[64];
    __shared__ float nm2[64];
    if (tid < 64) sa[tid] = amps[b * 64 + tid];
    else if (tid < 128) nm2[tid - 64] = nmag[b * 64 + (tid - 64)];
    __syncthreads();
    int t = blockIdx.x * 256 + tid;
    float f0v = f0[(size_t)b * T0 + t];
    // u = f0 * t * 4/63999 (linspace incl endpoint); frac in double, per-harmonic
    // frac(h*uf) exact enough in fp32 since uf in [0,1).
    double u = (double)f0v * ((double)t * (4.0 / 63999.0));
    float uf = (float)(u - floor(u));
    float acc = 0.f;
    #pragma unroll
    for (int h = 1; h <= 64; ++h) {
        float x = uf * (float)h;
        x = x - floorf(x);
        acc = fmaf(sa[h - 1], __builtin_amdgcn_sinf(x), acc);   // sin(2*pi*x)
    }
    out[(size_t)b * T0 + t] = acc + wn[(size_t)b * T0 + t] * nm2[t / 1000];
}

extern "C" void kernel_launch(void* const* d_in, const int* in_sizes, int n_in,
                              void* d_out, int out_size, void* d_ws, size_t ws_size,
                              hipStream_t stream) {
    const float* audio = (const float*)d_in[0];
    const float* f0    = (const float*)d_in[1];
    const float* wn    = (const float*)d_in[2];
    const float* w1    = (const float*)d_in[3];
    const float* b1    = (const float*)d_in[4];
    const float* w2    = (const float*)d_in[5];
    const float* b2    = (const float*)d_in[6];
    const float* w3    = (const float*)d_in[7];
    const float* b3    = (const float*)d_in[8];
    const float* wl    = (const float*)d_in[9];
    const float* bl    = (const float*)d_in[10];
    float* out = (float*)d_out;

    char* ws = (char*)d_ws;
    float* pooled  = (float*)(ws);                 // 2048 f32 (zeroed by prep)
    float* amps    = (float*)(ws + 8192);          // 1024 f32
    float* nmag    = (float*)(ws + 12288);         // 1024 f32
    int*   counter = (int*)(ws + 16384);           // 1 int (zeroed by prep)
    u16* a2t = (u16*)(ws + 16448);                 // 18432 u16
    u16* a3t = (u16*)(ws + 16448 + 36864);         // 73728 u16

    prep_w_k<<<369, 256, 0, stream>>>(w2, w3, a2t, a3t, pooled, counter);
    mega_k<<<dim3(NBLKX, BATCH), 512, 0, stream>>>(audio, w1, b1, a2t, b2, a3t, b3,
                                                   pooled, counter, wl, bl, amps, nmag);
    synth_k<<<dim3(T0 / 256, BATCH), 256, 0, stream>>>(f0, wn, amps, nmag, out);
}